// Round 1
// baseline (143.100 us; speedup 1.0000x reference)
//
#include <hip/hip_runtime.h>

#define B_    16
#define CIN   64
#define COUT  128
#define H_    32
#define W_    32
#define KK    576   // CIN * 3 * 3
#define TCO   16    // couts per thread in conv kernel

// ---------------------------------------------------------------------------
// Stage 1: global max(|x|), max(|w|) via block reduce + atomicMax on fp32 bits
// (all values >= 0 so the uint bit pattern is order-preserving).
// ---------------------------------------------------------------------------
__global__ __launch_bounds__(256) void maxabs_kernel(
    const float* __restrict__ x, const float* __restrict__ w,
    float* __restrict__ scales) {
  const int nx = B_ * CIN * H_ * W_;
  const int nw = COUT * KK;
  const int stride = gridDim.x * blockDim.x;
  float mx = 0.0f, mw = 0.0f;
  for (int i = blockIdx.x * blockDim.x + threadIdx.x; i < nx; i += stride)
    mx = fmaxf(mx, fabsf(x[i]));
  for (int i = blockIdx.x * blockDim.x + threadIdx.x; i < nw; i += stride)
    mw = fmaxf(mw, fabsf(w[i]));
#pragma unroll
  for (int off = 32; off > 0; off >>= 1) {
    mx = fmaxf(mx, __shfl_down(mx, off, 64));
    mw = fmaxf(mw, __shfl_down(mw, off, 64));
  }
  __shared__ float smx[4], smw[4];
  const int wid = threadIdx.x >> 6;
  if ((threadIdx.x & 63) == 0) { smx[wid] = mx; smw[wid] = mw; }
  __syncthreads();
  if (threadIdx.x == 0) {
#pragma unroll
    for (int i = 1; i < 4; ++i) { mx = fmaxf(mx, smx[i]); mw = fmaxf(mw, smw[i]); }
    atomicMax((unsigned int*)&scales[0], __float_as_uint(mx));
    atomicMax((unsigned int*)&scales[1], __float_as_uint(mw));
  }
}

// ---------------------------------------------------------------------------
// Stage 2: quantize. Must mirror the reference exactly:
//   scale = max/127 (IEEE div), q = rint(x/scale) (round-half-even), clip +-127
// qx kept in [B][CIN][H][W] layout as fp32-held small integers (exact FMA math).
// qw transposed to [K=576][COUT=128] so conv weight rows are contiguous.
// ---------------------------------------------------------------------------
__global__ __launch_bounds__(256) void quant_kernel(
    const float* __restrict__ x, const float* __restrict__ w,
    const float* __restrict__ scales,
    float* __restrict__ qx, float* __restrict__ qw) {
  const int i = blockIdx.x * blockDim.x + threadIdx.x;
  const int nx = B_ * CIN * H_ * W_;
  const int nw = COUT * KK;
  if (i < nx) {
    const float s = scales[0] / 127.0f;
    float q = rintf(x[i] / s);
    qx[i] = fminf(fmaxf(q, -127.0f), 127.0f);
  }
  if (i < nw) {
    const float s = scales[1] / 127.0f;
    float q = rintf(w[i] / s);
    q = fminf(fmaxf(q, -127.0f), 127.0f);
    const int o = i / KK;
    const int k = i - o * KK;
    qw[k * COUT + o] = q;   // wm[k, o]
  }
}

// ---------------------------------------------------------------------------
// Stage 3: direct conv == integer GEMM in fp32 FMA (exact, all ints < 2^24).
// Block: 32x8 pixel tile, fixed batch b and 16-cout group. Each thread owns
// one output pixel x 16 couts. Weight row pointer is block-uniform -> scalar
// loads on the SALU pipe; qx loads are coalesced along tx.
// ---------------------------------------------------------------------------
__global__ __launch_bounds__(256) void conv_kernel(
    const float* __restrict__ qx, const float* __restrict__ qw,
    const float* __restrict__ scales, const float* __restrict__ bias,
    float* __restrict__ out) {
  const int tx = threadIdx.x;            // 0..31 (== output x)
  const int y  = blockIdx.x * 8 + threadIdx.y;
  const int ob = blockIdx.y * TCO;       // cout group base
  const int b  = blockIdx.z;

  float acc[TCO];
#pragma unroll
  for (int i = 0; i < TCO; ++i) acc[i] = 0.0f;

  const float* __restrict__ xb = qx + b * (CIN * H_ * W_);
  for (int cin = 0; cin < CIN; ++cin) {
    const float* __restrict__ xc = xb + cin * (H_ * W_);
#pragma unroll
    for (int kh = 0; kh < 3; ++kh) {
      const int yy = y + kh - 1;
      if (yy < 0 || yy >= H_) continue;
#pragma unroll
      for (int kw = 0; kw < 3; ++kw) {
        const int xx = tx + kw - 1;
        const float v = (xx >= 0 && xx < W_) ? xc[yy * W_ + xx] : 0.0f;
        const float* __restrict__ wr =
            qw + (cin * 9 + kh * 3 + kw) * COUT + ob;  // block-uniform address
#pragma unroll
        for (int oi = 0; oi < TCO; ++oi)
          acc[oi] = fmaf(v, wr[oi], acc[oi]);
      }
    }
  }

  const float s = (scales[0] / 127.0f) * (scales[1] / 127.0f);
  const int l = y * W_ + tx;
#pragma unroll
  for (int oi = 0; oi < TCO; ++oi)
    out[(b * COUT + ob + oi) * (H_ * W_) + l] = s * acc[oi] + bias[ob + oi];
}

// ---------------------------------------------------------------------------
extern "C" void kernel_launch(void* const* d_in, const int* in_sizes, int n_in,
                              void* d_out, int out_size, void* d_ws, size_t ws_size,
                              hipStream_t stream) {
  const float* x    = (const float*)d_in[0];
  const float* w    = (const float*)d_in[1];
  const float* bias = (const float*)d_in[2];
  float* out = (float*)d_out;

  // workspace layout: [0..255] scale slots | qx (4 MiB fp32) | qw (288 KiB fp32)
  float* scales = (float*)d_ws;
  float* qx = (float*)((char*)d_ws + 256);
  float* qw = qx + (size_t)B_ * CIN * H_ * W_;

  hipMemsetAsync(d_ws, 0, 256, stream);  // zero the atomicMax slots

  maxabs_kernel<<<256, 256, 0, stream>>>(x, w, scales);

  const int nq = B_ * CIN * H_ * W_;  // covers nw=73728 too
  quant_kernel<<<(nq + 255) / 256, 256, 0, stream>>>(x, w, scales, qx, qw);

  dim3 grid(H_ / 8, COUT / TCO, B_);   // (4, 8, 16)
  dim3 block(W_, 8);                   // (32, 8) = 256 threads
  conv_kernel<<<grid, block, 0, stream>>>(qx, qw, scales, bias, out);
}

// Round 2
// 85.725 us; speedup vs baseline: 1.6693x; 1.6693x over previous
//
#include <hip/hip_runtime.h>
#include <hip/hip_bf16.h>

#define B_    16
#define CIN   64
#define COUT  128
#define H_    32
#define W_    32

typedef __attribute__((ext_vector_type(8))) short short8;   // 8 bf16 = 4 VGPRs
typedef __attribute__((ext_vector_type(4))) float float4v;  // MFMA C/D frag

// float -> bf16 bits; exact for small integers (|q| <= 127 fits 7 mantissa bits)
__device__ __forceinline__ unsigned short f2bf(float q) {
  return (unsigned short)(__builtin_bit_cast(unsigned int, q) >> 16);
}

// ---------------------------------------------------------------------------
// Stage 1: global max|x|, max|w| -> scales[0], scales[1] (fp32 bits, atomicMax
// on uint works since all values are >= 0).
// ---------------------------------------------------------------------------
__global__ __launch_bounds__(256) void maxabs_kernel(
    const float* __restrict__ x, const float* __restrict__ w,
    float* __restrict__ scales) {
  const int nx = B_ * CIN * H_ * W_;
  const int nw = COUT * CIN * 9;
  const int stride = gridDim.x * blockDim.x;
  float mx = 0.0f, mw = 0.0f;
  for (int i = blockIdx.x * blockDim.x + threadIdx.x; i < nx; i += stride)
    mx = fmaxf(mx, fabsf(x[i]));
  for (int i = blockIdx.x * blockDim.x + threadIdx.x; i < nw; i += stride)
    mw = fmaxf(mw, fabsf(w[i]));
#pragma unroll
  for (int off = 32; off > 0; off >>= 1) {
    mx = fmaxf(mx, __shfl_down(mx, off, 64));
    mw = fmaxf(mw, __shfl_down(mw, off, 64));
  }
  __shared__ float smx[4], smw[4];
  const int wid = threadIdx.x >> 6;
  if ((threadIdx.x & 63) == 0) { smx[wid] = mx; smw[wid] = mw; }
  __syncthreads();
  if (threadIdx.x == 0) {
#pragma unroll
    for (int i = 1; i < 4; ++i) { mx = fmaxf(mx, smx[i]); mw = fmaxf(mw, smw[i]); }
    atomicMax((unsigned int*)&scales[0], __float_as_uint(mx));
    atomicMax((unsigned int*)&scales[1], __float_as_uint(mw));
  }
}

// ---------------------------------------------------------------------------
// Stage 2 (fused): quantize exactly like the reference (IEEE div by max/127,
// rintf = round-half-even, clip +-127) and repack:
//   qx: bf16 [B][H][W][CIN]      (channels-last, via LDS transpose)
//   qw: bf16 [kh*3+kw][COUT][CIN]
// Blocks 0..511: one (b, y) row of x. Blocks 512..799: weights.
// ---------------------------------------------------------------------------
__global__ __launch_bounds__(256) void quant_pack_kernel(
    const float* __restrict__ x, const float* __restrict__ w,
    const float* __restrict__ scales,
    unsigned short* __restrict__ qx, unsigned short* __restrict__ qw) {
  __shared__ __align__(16) unsigned short lds[W_ * 72];  // [x][cin], pad 64->72
  const int t = threadIdx.x;
  const int bb = blockIdx.x;
  if (bb < 512) {
    const int b = bb >> 5, y = bb & 31;
    const float s = scales[0] / 127.0f;
#pragma unroll
    for (int k = 0; k < 8; ++k) {
      const int u = t + k * 256;           // u in [0, 2048)
      const int cin = u >> 5, xx = u & 31; // coalesced read along x
      float q = rintf(x[((b * CIN + cin) * H_ + y) * W_ + xx] / s);
      q = fminf(fmaxf(q, -127.0f), 127.0f);
      lds[xx * 72 + cin] = f2bf(q);
    }
    __syncthreads();
    // coalesced 16B store: thread t writes pixel xx=t>>3, cins [(t&7)*8, +8)
    const int xx = t >> 3, c0 = (t & 7) * 8;
    *(uint4*)(qx + (((b * H_ + y) * W_ + xx) << 6) + c0) =
        *(const uint4*)(&lds[xx * 72 + c0]);
  } else {
    const int i = (bb - 512) * 256 + t;    // < 73728
    const float s = scales[1] / 127.0f;
    float q = rintf(w[i] / s);
    q = fminf(fmaxf(q, -127.0f), 127.0f);
    // i = ((o*64 + c)*3 + kh)*3 + kw
    const int kw = i % 3; int j = i / 3;
    const int kh = j % 3; j /= 3;
    const int c = j & 63; const int o = j >> 6;
    qw[(kh * 3 + kw) * (COUT * CIN) + o * CIN + c] = f2bf(q);
  }
}

// ---------------------------------------------------------------------------
// Stage 3: conv as bf16 MFMA GEMM (exact: all operands are small integers,
// partial sums < 2^24). Block = 64 pixels (2 image rows) x 128 couts, 4 waves;
// wave w owns couts [w*32, w*32+32). Per K-step (9 spatial x 2 cin-halves):
//   A (couts x cin)  : 2 direct dwordx4 loads from qw (L2-resident)
//   B (cin x pixels) : 4 predicated dwordx4 loads from qx (channels-last)
//   8 x mfma_f32_16x16x32_bf16
// D layout (verified): col = lane&15 = pixel x, row = quad*4+reg = cout
// -> epilogue stores are 64B-coalesced per quad.
// ---------------------------------------------------------------------------
__global__ __launch_bounds__(256, 1) void conv_mfma_kernel(
    const unsigned short* __restrict__ qx,  // [16][32][32][64]
    const unsigned short* __restrict__ qw,  // [9][128][64]
    const float* __restrict__ scales, const float* __restrict__ bias,
    float* __restrict__ out) {
  const int tid  = threadIdx.x;
  const int wave = tid >> 6;
  const int lane = tid & 63;
  const int n16  = lane & 15;
  const int quad = lane >> 4;
  const int y0   = blockIdx.x * 2;   // 16 ytiles
  const int b    = blockIdx.y;       // 16 batches
  const int cout0 = wave * 32;

  float4v acc[4][2];
#pragma unroll
  for (int g = 0; g < 4; ++g)
#pragma unroll
    for (int t = 0; t < 2; ++t) acc[g][t] = (float4v)0.0f;

  for (int s = 0; s < 9; ++s) {
    const int kh = s / 3, kw = s - 3 * (s / 3);
#pragma unroll
    for (int half = 0; half < 2; ++half) {
      short8 af[2];
#pragma unroll
      for (int t = 0; t < 2; ++t)
        af[t] = *(const short8*)(qw + s * (COUT * CIN) +
                                 (cout0 + t * 16 + n16) * CIN + half * 32 + quad * 8);
      short8 bfr[4];
#pragma unroll
      for (int g = 0; g < 4; ++g) {
        const int yy = y0 + (g >> 1) + kh - 1;
        const int xx = (g & 1) * 16 + n16 + kw - 1;
        short8 v = (short8)0;
        if (yy >= 0 && yy < H_ && xx >= 0 && xx < W_)
          v = *(const short8*)(qx + (((b * H_ + yy) * W_ + xx) << 6) +
                               half * 32 + quad * 8);
        bfr[g] = v;
      }
#pragma unroll
      for (int g = 0; g < 4; ++g)
#pragma unroll
        for (int t = 0; t < 2; ++t)
          acc[g][t] = __builtin_amdgcn_mfma_f32_16x16x32_bf16(
              af[t], bfr[g], acc[g][t], 0, 0, 0);
    }
  }

  const float sc = (scales[0] / 127.0f) * (scales[1] / 127.0f);
#pragma unroll
  for (int g = 0; g < 4; ++g) {
    const int y = y0 + (g >> 1);
    const int xb = (g & 1) * 16;
#pragma unroll
    for (int t = 0; t < 2; ++t) {
#pragma unroll
      for (int r = 0; r < 4; ++r) {
        const int cout = cout0 + t * 16 + quad * 4 + r;
        out[((b * COUT + cout) << 10) + y * W_ + xb + n16] =
            sc * acc[g][t][r] + bias[cout];
      }
    }
  }
}

// ---------------------------------------------------------------------------
extern "C" void kernel_launch(void* const* d_in, const int* in_sizes, int n_in,
                              void* d_out, int out_size, void* d_ws, size_t ws_size,
                              hipStream_t stream) {
  const float* x    = (const float*)d_in[0];
  const float* w    = (const float*)d_in[1];
  const float* bias = (const float*)d_in[2];
  float* out = (float*)d_out;

  // ws: [0..255] scale slots | qx bf16 (2 MiB) | qw bf16 (144 KiB)
  float* scales = (float*)d_ws;
  unsigned short* qx = (unsigned short*)((char*)d_ws + 256);
  unsigned short* qw = qx + (size_t)B_ * H_ * W_ * CIN;

  hipMemsetAsync(d_ws, 0, 256, stream);
  maxabs_kernel<<<128, 256, 0, stream>>>(x, w, scales);
  quant_pack_kernel<<<512 + 288, 256, 0, stream>>>(x, w, scales, qx, qw);
  conv_mfma_kernel<<<dim3(16, 16), 256, 0, stream>>>(qx, qw, scales, bias, out);
}

// Round 3
// 83.143 us; speedup vs baseline: 1.7211x; 1.0311x over previous
//
#include <hip/hip_runtime.h>

#define B_    16
#define CIN   64
#define COUT  128
#define H_    32
#define W_    32
#define HP    34           // halo-padded spatial dim
#define NPB   128          // maxabs grid blocks

typedef __attribute__((ext_vector_type(8)))  short  short8;    // 8 bf16 = 4 VGPRs
typedef __attribute__((ext_vector_type(16))) float  float16v;  // 32x32 MFMA C/D

// float -> bf16 bits; exact for small integers (|q| <= 127 needs 7 mantissa bits)
__device__ __forceinline__ unsigned short f2bf(float q) {
  return (unsigned short)(__builtin_bit_cast(unsigned int, q) >> 16);
}

// All-lanes max of a 128-entry array (written by maxabs), no LDS, no sync.
__device__ __forceinline__ float wave_max128(const float* __restrict__ p) {
  const int lane = threadIdx.x & 63;
  float m = fmaxf(p[lane], p[lane + 64]);
#pragma unroll
  for (int off = 32; off > 0; off >>= 1)
    m = fmaxf(m, __shfl_down(m, off, 64));
  return __shfl(m, 0, 64);
}

// ---------------------------------------------------------------------------
// Stage 1: per-block max|x|, max|w| -> bmx[blk], bmw[blk] (plain stores; no
// init needed, poison-safe). float4 loads.
// ---------------------------------------------------------------------------
__global__ __launch_bounds__(256) void maxabs_kernel(
    const float4* __restrict__ x4, const float4* __restrict__ w4,
    float* __restrict__ bmx, float* __restrict__ bmw) {
  const int nx4 = B_ * CIN * H_ * W_ / 4;   // 262144
  const int nw4 = COUT * CIN * 9 / 4;       // 18432
  const int tid = blockIdx.x * 256 + threadIdx.x;
  const int stride = NPB * 256;
  float mx = 0.0f, mw = 0.0f;
  for (int i = tid; i < nx4; i += stride) {
    float4 v = x4[i];
    mx = fmaxf(mx, fmaxf(fmaxf(fabsf(v.x), fabsf(v.y)),
                         fmaxf(fabsf(v.z), fabsf(v.w))));
  }
  for (int i = tid; i < nw4; i += stride) {
    float4 v = w4[i];
    mw = fmaxf(mw, fmaxf(fmaxf(fabsf(v.x), fabsf(v.y)),
                         fmaxf(fabsf(v.z), fabsf(v.w))));
  }
#pragma unroll
  for (int off = 32; off > 0; off >>= 1) {
    mx = fmaxf(mx, __shfl_down(mx, off, 64));
    mw = fmaxf(mw, __shfl_down(mw, off, 64));
  }
  __shared__ float smx[4], smw[4];
  const int wid = threadIdx.x >> 6;
  if ((threadIdx.x & 63) == 0) { smx[wid] = mx; smw[wid] = mw; }
  __syncthreads();
  if (threadIdx.x == 0) {
#pragma unroll
    for (int i = 1; i < 4; ++i) { mx = fmaxf(mx, smx[i]); mw = fmaxf(mw, smw[i]); }
    bmx[blockIdx.x] = mx;
    bmw[blockIdx.x] = mw;
  }
}

// ---------------------------------------------------------------------------
// Stage 2 (fused): quantize exactly like the reference (IEEE div by max/127,
// rintf = round-half-even, clip +-127) and repack:
//   qx: bf16 [B][34][34][CIN]  halo-padded channels-last (LDS transpose)
//   qw: bf16 [kh*3+kw][COUT][CIN]
// Blocks [0,512): one (b,y) row of x.  [512,800): weights.  [800,866): zero halo.
// ---------------------------------------------------------------------------
__global__ __launch_bounds__(256) void quant_pack_kernel(
    const float* __restrict__ x, const float* __restrict__ w,
    const float* __restrict__ bmx, const float* __restrict__ bmw,
    unsigned short* __restrict__ qx, unsigned short* __restrict__ qw) {
  __shared__ __align__(16) unsigned short lds[W_ * 72];  // [x][cin], pad 64->72
  const int t = threadIdx.x;
  const int bb = blockIdx.x;
  if (bb < 512) {
    const int b = bb >> 5, y = bb & 31;
    const float s = wave_max128(bmx) / 127.0f;
#pragma unroll
    for (int k = 0; k < 8; ++k) {
      const int u = t + k * 256;            // [0, 2048)
      const int cin = u >> 5, xx = u & 31;  // coalesced along x
      float q = rintf(x[((b * CIN + cin) * H_ + y) * W_ + xx] / s);
      q = fminf(fmaxf(q, -127.0f), 127.0f);
      lds[xx * 72 + cin] = f2bf(q);
    }
    __syncthreads();
    const int xx = t >> 3, c0 = (t & 7) * 8;  // 16B coalesced store
    *(uint4*)(qx + ((size_t)(b * HP + y + 1) * HP + xx + 1) * 64 + c0) =
        *(const uint4*)(&lds[xx * 72 + c0]);
  } else if (bb < 800) {
    const int i = (bb - 512) * 256 + t;     // < 73728
    const float s = wave_max128(bmw) / 127.0f;
    float q = rintf(w[i] / s);
    q = fminf(fmaxf(q, -127.0f), 127.0f);
    // i = ((o*64 + c)*3 + kh)*3 + kw
    const int kw = i % 3; int j = i / 3;
    const int kh = j % 3; j /= 3;
    const int c = j & 63; const int o = j >> 6;
    qw[(kh * 3 + kw) * (COUT * CIN) + o * CIN + c] = f2bf(q);
  } else {
    // zero halo: 16896 uint4 slots, 1056 per batch
    const int v = (bb - 800) * 256 + t;
    const int b = v / 1056;
    const int r = v - b * 1056;
    const size_t base = (size_t)b * (HP * HP * 64);
    size_t off;
    if (r < 272)       off = base + (size_t)r * 8;                              // yy=0
    else if (r < 544)  off = base + (size_t)33 * (HP * 64) + (size_t)(r - 272) * 8;  // yy=33
    else if (r < 800) {
      const int i2 = r - 544;                                                   // xx=0
      off = base + (size_t)(1 + (i2 >> 3)) * (HP * 64) + (size_t)(i2 & 7) * 8;
    } else {
      const int i2 = r - 800;                                                   // xx=33
      off = base + (size_t)(1 + (i2 >> 3)) * (HP * 64) + 33 * 64 + (size_t)(i2 & 7) * 8;
    }
    uint4 z; z.x = z.y = z.z = z.w = 0;
    *(uint4*)(qx + off) = z;
  }
}

// ---------------------------------------------------------------------------
// Stage 3: conv as 32x32x16 bf16 MFMA (exact: integer operands, partials<2^24).
// Grid 512 blocks (32 y-rows x 16 b), 4 waves/block = 2 blocks/CU = 2 waves/SIMD.
// Wave = 32 pixels (one row) x 32 couts. Halo padding -> zero predication;
// all frag loads are direct dwordx4 (qw 144KB + qx rows stay L1/L2-resident).
// A frag: A[m=lane&31][k=(lane>>5)*8+j] = qw couts; B: B[k][n=lane&31] = pixels.
// D: col=lane&31 (pixel x), row=(reg&3)+8*(reg>>2)+4*(lane>>5) (cout).
// Two accumulator chains break MFMA dependency stalls (sum is exact).
// ---------------------------------------------------------------------------
__global__ __launch_bounds__(256, 2) void conv_mfma_kernel(
    const unsigned short* __restrict__ qx,  // [16][34][34][64]
    const unsigned short* __restrict__ qw,  // [9][128][64]
    const float* __restrict__ bmx, const float* __restrict__ bmw,
    const float* __restrict__ bias, float* __restrict__ out) {
  const int lane = threadIdx.x & 63;
  const int wv   = threadIdx.x >> 6;   // cout group
  const int col  = lane & 31;          // pixel x (B) / cout row (A)
  const int kb   = lane >> 5;          // k-half
  const int y    = blockIdx.x;
  const int b    = blockIdx.y;
  const int co0  = wv * 32;

  float16v acc0 = (float16v)0.0f, acc1 = (float16v)0.0f;

  const unsigned short* __restrict__ xb =
      qx + ((size_t)(b * HP + y) * HP + col) * 64 + kb * 8;   // (kh=0,kw=0) base
  const unsigned short* __restrict__ wb =
      qw + (size_t)(co0 + col) * 64 + kb * 8;

#pragma unroll
  for (int kh = 0; kh < 3; ++kh) {
#pragma unroll
    for (int kw = 0; kw < 3; ++kw) {
      const int s = kh * 3 + kw;
#pragma unroll
      for (int k16 = 0; k16 < 4; ++k16) {
        short8 a = *(const short8*)(wb + s * (COUT * CIN) + k16 * 16);
        short8 bf = *(const short8*)(xb + (kh * HP + kw) * 64 + k16 * 16);
        if (((s * 4 + k16) & 1) == 0)
          acc0 = __builtin_amdgcn_mfma_f32_32x32x16_bf16(a, bf, acc0, 0, 0, 0);
        else
          acc1 = __builtin_amdgcn_mfma_f32_32x32x16_bf16(a, bf, acc1, 0, 0, 0);
      }
    }
  }

  const float mx = wave_max128(bmx);
  const float mw = wave_max128(bmw);
  const float sc = (mx / 127.0f) * (mw / 127.0f);
  const float16v acc = acc0 + acc1;
#pragma unroll
  for (int r = 0; r < 16; ++r) {
    const int row  = (r & 3) + 8 * (r >> 2) + 4 * kb;
    const int cout = co0 + row;
    out[((b * COUT + cout) << 10) + y * W_ + col] = sc * acc[r] + bias[cout];
  }
}

// ---------------------------------------------------------------------------
extern "C" void kernel_launch(void* const* d_in, const int* in_sizes, int n_in,
                              void* d_out, int out_size, void* d_ws, size_t ws_size,
                              hipStream_t stream) {
  const float* x    = (const float*)d_in[0];
  const float* w    = (const float*)d_in[1];
  const float* bias = (const float*)d_in[2];
  float* out = (float*)d_out;

  // ws: bmx[128] | bmw[128] | qx bf16 [16][34][34][64] (2.37 MB) | qw bf16 (144 KB)
  float* bmx = (float*)d_ws;
  float* bmw = bmx + 128;
  unsigned short* qx = (unsigned short*)((char*)d_ws + 1024);
  unsigned short* qw = qx + (size_t)B_ * HP * HP * CIN;

  maxabs_kernel<<<NPB, 256, 0, stream>>>((const float4*)x, (const float4*)w,
                                         bmx, bmw);
  quant_pack_kernel<<<866, 256, 0, stream>>>(x, w, bmx, bmw, qx, qw);
  conv_mfma_kernel<<<dim3(32, 16), 256, 0, stream>>>(qx, qw, bmx, bmw, bias, out);
}

// Round 4
// 75.848 us; speedup vs baseline: 1.8867x; 1.0962x over previous
//
#include <hip/hip_runtime.h>

#define B_    16
#define CIN   64
#define COUT  128
#define H_    32
#define W_    32
#define HP    34           // halo-padded spatial dim
#define XROW  2176         // shorts per padded qx row = 272 chunks * 8
#define NPB   256          // maxabs grid blocks

typedef __attribute__((ext_vector_type(8)))  short  short8;    // 8 bf16 = 4 VGPRs
typedef __attribute__((ext_vector_type(16))) float  float16v;  // 32x32 MFMA C/D

// float -> bf16 bits; exact for small integers (|q| <= 127 needs 7 mantissa bits)
__device__ __forceinline__ unsigned short f2bf(float q) {
  return (unsigned short)(__builtin_bit_cast(unsigned int, q) >> 16);
}

// All-lanes max of a 256-entry array (written by maxabs), no LDS, no sync.
__device__ __forceinline__ float wave_max256(const float* __restrict__ p) {
  const int lane = threadIdx.x & 63;
  float m = fmaxf(fmaxf(p[lane], p[lane + 64]),
                  fmaxf(p[lane + 128], p[lane + 192]));
#pragma unroll
  for (int off = 32; off > 0; off >>= 1)
    m = fmaxf(m, __shfl_down(m, off, 64));
  return __shfl(m, 0, 64);
}

// ---------------------------------------------------------------------------
// Stage 1: per-block max|x|, max|w| -> bmx[256], bmw[256] (plain stores, no
// init needed, poison-safe). float4 loads, 256 blocks = 1 per CU.
// ---------------------------------------------------------------------------
__global__ __launch_bounds__(256) void maxabs_kernel(
    const float4* __restrict__ x4, const float4* __restrict__ w4,
    float* __restrict__ bmx, float* __restrict__ bmw) {
  const int nx4 = B_ * CIN * H_ * W_ / 4;   // 262144
  const int nw4 = COUT * CIN * 9 / 4;       // 18432
  const int tid = blockIdx.x * 256 + threadIdx.x;
  const int stride = NPB * 256;             // 65536
  float mx = 0.0f, mw = 0.0f;
#pragma unroll
  for (int k = 0; k < 4; ++k) {             // nx4 / stride == 4 exactly
    float4 v = x4[tid + k * stride];
    mx = fmaxf(mx, fmaxf(fmaxf(fabsf(v.x), fabsf(v.y)),
                         fmaxf(fabsf(v.z), fabsf(v.w))));
  }
  if (tid < nw4) {
    float4 v = w4[tid];
    mw = fmaxf(mw, fmaxf(fmaxf(fabsf(v.x), fabsf(v.y)),
                         fmaxf(fabsf(v.z), fabsf(v.w))));
  }
#pragma unroll
  for (int off = 32; off > 0; off >>= 1) {
    mx = fmaxf(mx, __shfl_down(mx, off, 64));
    mw = fmaxf(mw, __shfl_down(mw, off, 64));
  }
  __shared__ float smx[4], smw[4];
  const int wid = threadIdx.x >> 6;
  if ((threadIdx.x & 63) == 0) { smx[wid] = mx; smw[wid] = mw; }
  __syncthreads();
  if (threadIdx.x == 0) {
#pragma unroll
    for (int i = 1; i < 4; ++i) { mx = fmaxf(mx, smx[i]); mw = fmaxf(mw, smw[i]); }
    bmx[blockIdx.x] = mx;
    bmw[blockIdx.x] = mw;
  }
}

// ---------------------------------------------------------------------------
// Stage 2 (fused): quantize exactly like the reference (IEEE div by max/127,
// rintf = round-half-even, clip +-127) and repack into MFMA-lane-ordered
// layouts (so conv's frag loads are contiguous per half-wave):
//   qx: bf16 [B][y:34][k16:4][kb:2][xs:34][8 cin]   (halo-padded)
//   qw: bf16 [s:9][k16:4][kb:2][cout:128][8 cin]
// Blocks [0,512): one (b,y) row of x.  [512,544): zero halo rows.
// [544,832): weights.
// ---------------------------------------------------------------------------
__global__ __launch_bounds__(256) void quant_pack_kernel(
    const float* __restrict__ x, const float* __restrict__ w,
    const float* __restrict__ bmx, const float* __restrict__ bmw,
    unsigned short* __restrict__ qx, unsigned short* __restrict__ qw) {
  __shared__ __align__(16) unsigned short lds[W_ * 72];  // [x][cin], pad 64->72
  const int t = threadIdx.x;
  const int bb = blockIdx.x;
  if (bb < 512) {
    const int b = bb >> 5, y = bb & 31;
    const float s = wave_max256(bmx) / 127.0f;
#pragma unroll
    for (int k = 0; k < 8; ++k) {
      const int u = t + k * 256;            // [0, 2048)
      const int cin = u >> 5, xx = u & 31;  // coalesced along x
      float q = rintf(x[((b * CIN + cin) * H_ + y) * W_ + xx] / s);
      q = fminf(fmaxf(q, -127.0f), 127.0f);
      lds[xx * 72 + cin] = f2bf(q);
    }
    __syncthreads();
    // write 272 16-B chunks: c = ((k16*2+kb)*34 + xs); fully coalesced.
    const size_t row = (size_t)(b * HP + y + 1) * XROW;
    for (int c = t; c < 272; c += 256) {
      const int k16 = c / 68;
      const int r   = c - k16 * 68;
      const int kbh = r / 34;
      const int xs  = r - kbh * 34;
      uint4 v; v.x = v.y = v.z = v.w = 0;
      if (xs >= 1 && xs <= 32)
        v = *(const uint4*)(&lds[(xs - 1) * 72 + k16 * 16 + kbh * 8]);
      *(uint4*)(qx + row + (size_t)c * 8) = v;
    }
  } else if (bb < 544) {
    // zero halo rows: idx -> (b, yy in {0,33})
    const int idx = bb - 512;
    const int b = idx >> 1, yy = (idx & 1) ? 33 : 0;
    const size_t row = (size_t)(b * HP + yy) * XROW;
    uint4 z; z.x = z.y = z.z = z.w = 0;
    for (int c = t; c < 272; c += 256)
      *(uint4*)(qx + row + (size_t)c * 8) = z;
  } else {
    const int i = (bb - 544) * 256 + t;     // < 73728
    const float s = wave_max256(bmw) / 127.0f;
    float q = rintf(w[i] / s);
    q = fminf(fmaxf(q, -127.0f), 127.0f);
    // i = ((o*64 + c)*3 + kh)*3 + kw
    const int kw = i % 3; int j = i / 3;
    const int kh = j % 3; j /= 3;
    const int c = j & 63; const int o = j >> 6;
    const int sidx = kh * 3 + kw;
    const int k16 = c >> 4, kb2 = (c >> 3) & 1, e = c & 7;
    qw[(size_t)((((sidx * 4 + k16) * 2 + kb2) * 128 + o)) * 8 + e] = f2bf(q);
  }
}

// ---------------------------------------------------------------------------
// Stage 3: conv as 32x32x16 bf16 MFMA (exact: integer operands, partials<2^24).
// Grid 512 (32 y x 16 b), 4 waves/block (cout groups), 2 blocks/CU.
// Wave = 32 pixels (one row) x 32 couts. Both frag loads are CONTIGUOUS per
// half-wave (512 B) thanks to the lane-ordered qx/qw layouts; the 4 waves of a
// block load identical qx lines (L1 broadcast). Halo padding -> no predication.
// A frag: A[m=lane&31][k=(lane>>5)*8+j]; B: B[k][n=lane&31].
// D: col=lane&31 (pixel x), row=(reg&3)+8*(reg>>2)+4*(lane>>5) (cout).
// Two accumulator chains break MFMA dependency stalls (sum is exact).
// ---------------------------------------------------------------------------
__global__ __launch_bounds__(256, 2) void conv_mfma_kernel(
    const unsigned short* __restrict__ qx,  // [16][34][4][2][34][8]
    const unsigned short* __restrict__ qw,  // [9][4][2][128][8]
    const float* __restrict__ bmx, const float* __restrict__ bmw,
    const float* __restrict__ bias, float* __restrict__ out) {
  const int lane = threadIdx.x & 63;
  const int wv   = threadIdx.x >> 6;   // cout group
  const int col  = lane & 31;          // pixel x (B) / cout row (A)
  const int kb   = lane >> 5;          // k-half
  const int y    = blockIdx.x;
  const int b    = blockIdx.y;
  const int co0  = wv * 32;

  float16v acc0 = (float16v)0.0f, acc1 = (float16v)0.0f;

  const unsigned short* __restrict__ xp =
      qx + (size_t)b * HP * XROW + kb * 272 + col * 8;   // + (y+kh)*XROW + k16*544 + kw*8
  const unsigned short* __restrict__ wp =
      qw + kb * 1024 + (co0 + col) * 8;                  // + (s*4+k16)*2048

#pragma unroll
  for (int kh = 0; kh < 3; ++kh) {
    const unsigned short* __restrict__ xr = xp + (size_t)(y + kh) * XROW;
#pragma unroll
    for (int kw = 0; kw < 3; ++kw) {
      const int s = kh * 3 + kw;
#pragma unroll
      for (int k16 = 0; k16 < 4; ++k16) {
        short8 a  = *(const short8*)(wp + (s * 4 + k16) * 2048);
        short8 bf = *(const short8*)(xr + k16 * 544 + kw * 8);
        if (((s * 4 + k16) & 1) == 0)
          acc0 = __builtin_amdgcn_mfma_f32_32x32x16_bf16(a, bf, acc0, 0, 0, 0);
        else
          acc1 = __builtin_amdgcn_mfma_f32_32x32x16_bf16(a, bf, acc1, 0, 0, 0);
      }
    }
  }

  const float mx = wave_max256(bmx);
  const float mw = wave_max256(bmw);
  const float sc = (mx / 127.0f) * (mw / 127.0f);
  const float16v acc = acc0 + acc1;
#pragma unroll
  for (int r = 0; r < 16; ++r) {
    const int row  = (r & 3) + 8 * (r >> 2) + 4 * kb;
    const int cout = co0 + row;
    out[((b * COUT + cout) << 10) + y * W_ + col] = sc * acc[r] + bias[cout];
  }
}

// ---------------------------------------------------------------------------
extern "C" void kernel_launch(void* const* d_in, const int* in_sizes, int n_in,
                              void* d_out, int out_size, void* d_ws, size_t ws_size,
                              hipStream_t stream) {
  const float* x    = (const float*)d_in[0];
  const float* w    = (const float*)d_in[1];
  const float* bias = (const float*)d_in[2];
  float* out = (float*)d_out;

  // ws: bmx[256] | bmw[256] | qx bf16 [16][34][272][8] (2.37 MB) | qw bf16 (147 KB)
  float* bmx = (float*)d_ws;
  float* bmw = bmx + 256;
  unsigned short* qx = (unsigned short*)((char*)d_ws + 2048);
  unsigned short* qw = qx + (size_t)B_ * HP * XROW;

  maxabs_kernel<<<NPB, 256, 0, stream>>>((const float4*)x, (const float4*)w,
                                         bmx, bmw);
  quant_pack_kernel<<<832, 256, 0, stream>>>(x, w, bmx, bmw, qx, qw);
  conv_mfma_kernel<<<dim3(32, 16), 256, 0, stream>>>(qx, qw, bmx, bmw, bias, out);
}